// Round 6
// baseline (2136.238 us; speedup 1.0000x reference)
//
#include <hip/hip_runtime.h>

// DRNN: 4-layer dilated LSTM, T=2048, dil {1,2,4,8}, dims 256->128->128->128->256.
//
// Round-6: fp16-dot2 dataflow pipeline, 39 persistent blocks x 512 threads.
//   R0 | R1 x2 (Wih inlined) | R2 x4 (Wih inlined) | R3 x32 (8 chains x 4 quarters)
// Streamer stages removed: each recurrent block computes its own Wih@v with
// v_dot2_f32_f16 (2 MAC/lane/cyc; fp16 weights in regs, fp16 h/v in LDS, fp32
// accum). Cross-block elements are ONE u32: (tag16<<16)|fp16, relaxed
// system-scope atomics (MALL coherence). tag16 = j+1 (signed compare: poison
// 0xAAAA = -21846 => not ready). Barriers are raw s_barrier+lgkmcnt only (no
// vmcnt drain). Ring guards poll consumer OUTPUT tags at 224-step slack on
// 256-slot rings. Every poll has a budget: failure = wrong answer, never hang.

typedef unsigned int u32;
typedef _Float16 h2v __attribute__((ext_vector_type(2)));

#define TSTEPS 2048

// ws layout: float zx[2048*512], then u32 region
#define ZX_FLOATS 1048576
#define Y0_OFF 0       // 256*128 u32
#define Y1_OFF 32768   // 256*128
#define Y2_OFF 65536   // 256*128
#define HX_OFF 98304   // 256*256

__device__ __forceinline__ void barL() {
  asm volatile("s_waitcnt lgkmcnt(0)\ns_barrier" ::: "memory");
}
__device__ __forceinline__ float f_sig(float x) { return 1.0f / (1.0f + __expf(-x)); }
__device__ __forceinline__ float f_tanh(float x) {
  float xc = fminf(fmaxf(x, -15.0f), 15.0f);
  float e = __expf(2.0f * xc);
  return (e - 1.0f) / (e + 1.0f);
}
__device__ __forceinline__ u32 pld32(const u32* p) {
  return __hip_atomic_load((u32*)p, __ATOMIC_RELAXED, __HIP_MEMORY_SCOPE_SYSTEM);
}
__device__ __forceinline__ void pst16(u32* p, int j, float v) {
  _Float16 hv = (_Float16)v;
  u32 u = ((u32)(j + 1) << 16) | (u32)__builtin_bit_cast(unsigned short, hv);
  __hip_atomic_store(p, u, __ATOMIC_RELAXED, __HIP_MEMORY_SCOPE_SYSTEM);
}
__device__ __forceinline__ int ptag16(u32 u) { return (int)(short)(u >> 16); }
__device__ __forceinline__ _Float16 pval16(u32 u) {
  return __builtin_bit_cast(_Float16, (unsigned short)(u & 0xffffu));
}
__device__ __forceinline__ void ensure32(u32& u, const u32* p, int need, int& bud) {
  while (ptag16(u) < need) { if (--bud < 0) break; u = pld32(p); }
}
__device__ __forceinline__ void pollg32(const u32* p, int need, int& bud) {
  u32 g = pld32(p);
  while (ptag16(g) < need) { if (--bud < 0) break; g = pld32(p); }
}

// ---------------- kernel 1: zx[j][r] = Wih0[r,:]@x[j,:] + bih0[r] + bhh0[r] ----
__global__ __launch_bounds__(256) void zx0_kernel(
    const float* __restrict__ x, const float* __restrict__ Wih0,
    const float* __restrict__ bih0, const float* __restrict__ bhh0,
    float* __restrict__ zx) {
  __shared__ float xs[4 * 256];
  const int t = threadIdx.x;
  const int j0 = blockIdx.x * 4;
  ((float4*)xs)[t] = ((const float4*)(x + j0 * 256))[t];
  __syncthreads();
  const int r0 = t, r1 = t + 256;
  float a0[4] = {0, 0, 0, 0}, a1[4] = {0, 0, 0, 0};
  const float* w0p = Wih0 + r0 * 256;
  const float* w1p = Wih0 + r1 * 256;
#pragma unroll 8
  for (int k = 0; k < 256; k += 4) {
    float4 wa = *(const float4*)(w0p + k);
    float4 wb = *(const float4*)(w1p + k);
#pragma unroll
    for (int jj = 0; jj < 4; jj++) {
      float4 xv = *(const float4*)(xs + jj * 256 + k);
      a0[jj] += wa.x * xv.x + wa.y * xv.y + wa.z * xv.z + wa.w * xv.w;
      a1[jj] += wb.x * xv.x + wb.y * xv.y + wb.z * xv.z + wb.w * xv.w;
    }
  }
  float b0 = bih0[r0] + bhh0[r0];
  float b1 = bih0[r1] + bhh0[r1];
#pragma unroll
  for (int jj = 0; jj < 4; jj++) {
    zx[(j0 + jj) * 512 + r0] = a0[jj] + b0;
    zx[(j0 + jj) * 512 + r1] = a1[jj] + b1;
  }
}

// ---------------- R0: layer 0, dil 1. thread t = full-k row t ------------------
__device__ void r0_run(int t, const float* __restrict__ Whh0,
                       const float* __restrict__ h00, const float* __restrict__ c00,
                       const float* __restrict__ zx, u32* __restrict__ y0,
                       const u32* __restrict__ y1g, float* LDS) {
  _Float16* hb16 = (_Float16*)LDS;          // 128 cells (64 dwords)
  const h2v* hb2 = (const h2v*)LDS;
  float* zbuf = LDS + 64;                   // [512] (rows 128..511 used)
  h2v w[64];
#pragma unroll
  for (int kk = 0; kk < 128; kk += 4) {
    float4 a = *(const float4*)(Whh0 + t * 128 + kk);
    h2v t0; t0.x = (_Float16)a.x; t0.y = (_Float16)a.y;
    h2v t1; t1.x = (_Float16)a.z; t1.y = (_Float16)a.w;
    w[kk >> 1] = t0; w[(kk >> 1) + 1] = t1;
  }
  float c = 0.0f;
  if (t < 128) { hb16[t] = (_Float16)h00[t]; c = c00[t]; }
  int bud = 1 << 22;
  __syncthreads();
  float zxa = zx[t];
  for (int j = 0; j < TSTEPS; j++) {
    if (t == 256 && (j & 7) == 0 && j >= 240)  // ring guard: R1 consumed j-224
      pollg32(y1g + (u32)((j - 224) & 255) * 128, j - 223, bud);
    float acc = zxa;
#pragma unroll
    for (int kk = 0; kk < 64; kk++)
      acc = __builtin_amdgcn_fdot2(w[kk], hb2[kk], acc, false);
    if (j + 1 < TSTEPS) zxa = zx[(j + 1) * 512 + t];  // prefetch
    if (t >= 128) zbuf[t] = acc;
    barL();
    if (t < 128) {
      float zi = acc, zf = zbuf[t + 128], zg = zbuf[t + 256], zo = zbuf[t + 384];
      float ig = f_sig(zi), fg = f_sig(zf), gg = f_tanh(zg), og = f_sig(zo);
      c = fg * c + ig * gg;
      float h2 = og * f_tanh(c);
      hb16[t] = (_Float16)h2;
      pst16(y0 + (u32)(j & 255) * 128 + t, j, h2);  // fire & forget
    }
    barL();
  }
}

// ------- R1/R2: z = Wih@v[j] + b + Whh@h. D dil, GM guard mode -----------------
template <int D, int GM>
__device__ void rmid_run(int q, int t, const float* __restrict__ Wih,
                         const float* __restrict__ Whh,
                         const float* __restrict__ bih, const float* __restrict__ bhh,
                         const float* __restrict__ h0s, const float* __restrict__ c0s,
                         const u32* __restrict__ yin, u32* __restrict__ yout,
                         const u32* __restrict__ gptr, float* LDS) {
  _Float16* hb16 = (_Float16*)LDS;          // 128 cells
  const h2v* hb2 = (const h2v*)LDS;
  _Float16* vb16 = (_Float16*)(LDS + 64);   // 128 inputs
  const h2v* vb2 = (const h2v*)(LDS + 64);
  float* zbuf = LDS + 128;                  // [512]
  h2v wi[64], wh[64];
#pragma unroll
  for (int kk = 0; kk < 128; kk += 4) {
    float4 a = *(const float4*)(Wih + t * 128 + kk);
    h2v t0; t0.x = (_Float16)a.x; t0.y = (_Float16)a.y;
    h2v t1; t1.x = (_Float16)a.z; t1.y = (_Float16)a.w;
    wi[kk >> 1] = t0; wi[(kk >> 1) + 1] = t1;
    float4 b = *(const float4*)(Whh + t * 128 + kk);
    h2v t2; t2.x = (_Float16)b.x; t2.y = (_Float16)b.y;
    h2v t3; t3.x = (_Float16)b.z; t3.y = (_Float16)b.w;
    wh[kk >> 1] = t2; wh[(kk >> 1) + 1] = t3;
  }
  const float bst = bih[t] + bhh[t];
  float c = 0.0f;
  if (t < 128) { hb16[t] = (_Float16)h0s[q * 128 + t]; c = c0s[q * 128 + t]; }
  int bud = 1 << 22;
  u32 pf = 0;
  if (t < 128) pf = pld32(yin + (u32)(q & 255) * 128 + t);  // prime
  __syncthreads();
  const int NS = TSTEPS / D;
  for (int s = 0; s < NS; s++) {
    const int j = q + s * D;
    if (t < 128) {  // phase L: stage v[j] into LDS as fp16
      ensure32(pf, yin + (u32)(j & 255) * 128 + t, j + 1, bud);
      vb16[t] = pval16(pf);
    }
    barL();
    // guards: consumer progress at j-224 before slot overwrite
    if (GM == 1) {
      if (t == 256 && (s & 7) == 0 && j >= 232)
        pollg32(gptr + (u32)((j - 224) & 255) * 128, j - 223, bud);
    } else {
      if (t >= 256 && t < 260 && (s & 3) == 0 && j >= 232)
        pollg32(gptr + (u32)((j - 224) & 255) * 256 + (t - 256) * 64, j - 223, bud);
    }
    float acc = bst;
#pragma unroll
    for (int kk = 0; kk < 64; kk++)
      acc = __builtin_amdgcn_fdot2(wi[kk], vb2[kk], acc, false);
#pragma unroll
    for (int kk = 0; kk < 64; kk++)
      acc = __builtin_amdgcn_fdot2(wh[kk], hb2[kk], acc, false);
    if (t < 128 && s + 1 < NS)  // prefetch next own step's input
      pf = pld32(yin + (u32)((j + D) & 255) * 128 + t);
    if (t >= 128) zbuf[t] = acc;
    barL();
    if (t < 128) {
      float zi = acc, zf = zbuf[t + 128], zg = zbuf[t + 256], zo = zbuf[t + 384];
      float ig = f_sig(zi), fg = f_sig(zf), gg = f_tanh(zg), og = f_sig(zo);
      c = fg * c + ig * gg;
      float h2 = og * f_tanh(c);
      hb16[t] = (_Float16)h2;
      pst16(yout + (u32)(j & 255) * 128 + t, j, h2);
    }
    barL();
  }
}

// ---------------- R3: dil 8, chain q, quarter p, writes d_out ------------------
__device__ void r3_run(int q, int p, int t, const float* __restrict__ Wih3,
                       const float* __restrict__ Whh3,
                       const float* __restrict__ bih3, const float* __restrict__ bhh3,
                       const float* __restrict__ h03, const float* __restrict__ c03,
                       const u32* __restrict__ y2, u32* __restrict__ hx,
                       float* __restrict__ out, float* LDS) {
  _Float16* hb16 = (_Float16*)LDS;           // 256 cells (128 dwords)
  const h2v* hb2 = (const h2v*)LDS;
  _Float16* vb16 = (_Float16*)(LDS + 128);   // 128 inputs
  const h2v* vb2 = (const h2v*)(LDS + 128);
  float* zbuf = LDS + 192;                   // [512]
  const int lr = t & 255, half = t >> 8;
  const int ci = lr & 63;
  const int R = (lr >> 6) * 256 + p * 64 + ci;  // global z-row in [0,1024)
  h2v wh[64], wx[32];
#pragma unroll
  for (int kk = 0; kk < 128; kk += 4) {
    float4 a = *(const float4*)(Whh3 + R * 256 + half * 128 + kk);
    h2v t0; t0.x = (_Float16)a.x; t0.y = (_Float16)a.y;
    h2v t1; t1.x = (_Float16)a.z; t1.y = (_Float16)a.w;
    wh[kk >> 1] = t0; wh[(kk >> 1) + 1] = t1;
  }
#pragma unroll
  for (int kk = 0; kk < 64; kk += 4) {
    float4 a = *(const float4*)(Wih3 + R * 128 + half * 64 + kk);
    h2v t0; t0.x = (_Float16)a.x; t0.y = (_Float16)a.y;
    h2v t1; t1.x = (_Float16)a.z; t1.y = (_Float16)a.w;
    wx[kk >> 1] = t0; wx[(kk >> 1) + 1] = t1;
  }
  const float bst = (half == 0) ? (bih3[R] + bhh3[R]) : 0.0f;
  float c = (t < 64) ? c03[q * 256 + p * 64 + t] : 0.0f;
  if (t < 256) hb16[t] = (_Float16)h03[q * 256 + t];
  int bud = 1 << 22;
  const int pu = (t >= 64 && t < 256) ? (((t - 64) < p * 64) ? (t - 64) : (t - 64) + 64) : 0;
  u32 pf = 0;
  if (t < 128) pf = pld32(y2 + (u32)(q & 255) * 128 + t);
  __syncthreads();
#pragma unroll 1
  for (int s = 0; s < 256; s++) {
    const int j = q + 8 * s;
    if (t < 128) {
      ensure32(pf, y2 + (u32)(j & 255) * 128 + t, j + 1, bud);
      vb16[t] = pval16(pf);
    }
    barL();
    float acc = bst;
#pragma unroll
    for (int kk = 0; kk < 32; kk++)
      acc = __builtin_amdgcn_fdot2(wx[kk], vb2[half * 32 + kk], acc, false);
#pragma unroll
    for (int kk = 0; kk < 64; kk++)
      acc = __builtin_amdgcn_fdot2(wh[kk], hb2[half * 64 + kk], acc, false);
    if (t < 128 && s + 1 < 256) pf = pld32(y2 + (u32)((j + 8) & 255) * 128 + t);
    zbuf[half * 256 + lr] = acc;
    barL();
    if (t < 64) {
      float zi = zbuf[t] + zbuf[256 + t];
      float zf = zbuf[64 + t] + zbuf[320 + t];
      float zg = zbuf[128 + t] + zbuf[384 + t];
      float zo = zbuf[192 + t] + zbuf[448 + t];
      float ig = f_sig(zi), fg = f_sig(zf), gg = f_tanh(zg), og = f_sig(zo);
      c = fg * c + ig * gg;
      float h2 = og * f_tanh(c);
      out[j * 256 + p * 64 + t] = h2;                  // final output, fp32
      pst16(hx + (u32)(j & 255) * 256 + p * 64 + t, j, h2);  // peer broadcast
      hb16[p * 64 + t] = (_Float16)h2;
    }
    if (s + 1 < 256 && t >= 64 && t < 256) {  // gather 192 peer cells
      const u32* pp = hx + (u32)(j & 255) * 256 + pu;
      u32 hu = pld32(pp);
      while (ptag16(hu) < j + 1) { if (--bud < 0) break; hu = pld32(pp); }
      hb16[pu] = pval16(hu);
    }
    barL();
  }
}

// ---------------- persistent pipeline kernel -----------------------------------
__global__ __launch_bounds__(512, 2) void drnn_kernel(
    const float* __restrict__ Whh0, const float* __restrict__ h00, const float* __restrict__ c00,
    const float* __restrict__ Wih1, const float* __restrict__ Whh1,
    const float* __restrict__ bih1, const float* __restrict__ bhh1,
    const float* __restrict__ h01, const float* __restrict__ c01,
    const float* __restrict__ Wih2, const float* __restrict__ Whh2,
    const float* __restrict__ bih2, const float* __restrict__ bhh2,
    const float* __restrict__ h02, const float* __restrict__ c02,
    const float* __restrict__ Wih3, const float* __restrict__ Whh3,
    const float* __restrict__ bih3, const float* __restrict__ bhh3,
    const float* __restrict__ h03, const float* __restrict__ c03,
    float* __restrict__ ws, float* __restrict__ out) {
  __shared__ float LDS[704];
  const int b = blockIdx.x;
  const int t = threadIdx.x;
  const float* zx = ws;
  u32* base = (u32*)(ws + ZX_FLOATS);
  u32* y0 = base + Y0_OFF;
  u32* y1 = base + Y1_OFF;
  u32* y2 = base + Y2_OFF;
  u32* hx = base + HX_OFF;

  if (b == 0) {
    r0_run(t, Whh0, h00, c00, zx, y0, y1, LDS);
  } else if (b <= 2) {
    rmid_run<2, 1>(b - 1, t, Wih1, Whh1, bih1, bhh1, h01, c01, y0, y1, y2, LDS);
  } else if (b <= 6) {
    rmid_run<4, 2>(b - 3, t, Wih2, Whh2, bih2, bhh2, h02, c02, y1, y2, hx, LDS);
  } else {
    const int i = b - 7;
    r3_run(i >> 2, i & 3, t, Wih3, Whh3, bih3, bhh3, h03, c03, y2, hx, out, LDS);
  }
}

extern "C" void kernel_launch(void* const* d_in, const int* in_sizes, int n_in,
                              void* d_out, int out_size, void* d_ws, size_t ws_size,
                              hipStream_t stream) {
  const float* x    = (const float*)d_in[0];
  const float* Wih0 = (const float*)d_in[1];
  const float* Whh0 = (const float*)d_in[2];
  const float* bih0 = (const float*)d_in[3];
  const float* bhh0 = (const float*)d_in[4];
  const float* h00  = (const float*)d_in[5];
  const float* c00  = (const float*)d_in[6];
  const float* Wih1 = (const float*)d_in[7];
  const float* Whh1 = (const float*)d_in[8];
  const float* bih1 = (const float*)d_in[9];
  const float* bhh1 = (const float*)d_in[10];
  const float* h01  = (const float*)d_in[11];
  const float* c01  = (const float*)d_in[12];
  const float* Wih2 = (const float*)d_in[13];
  const float* Whh2 = (const float*)d_in[14];
  const float* bih2 = (const float*)d_in[15];
  const float* bhh2 = (const float*)d_in[16];
  const float* h02  = (const float*)d_in[17];
  const float* c02  = (const float*)d_in[18];
  const float* Wih3 = (const float*)d_in[19];
  const float* Whh3 = (const float*)d_in[20];
  const float* bih3 = (const float*)d_in[21];
  const float* bhh3 = (const float*)d_in[22];
  const float* h03  = (const float*)d_in[23];
  const float* c03  = (const float*)d_in[24];

  float* ws = (float*)d_ws;
  float* out = (float*)d_out;

  zx0_kernel<<<512, 256, 0, stream>>>(x, Wih0, bih0, bhh0, ws);
  drnn_kernel<<<39, 512, 0, stream>>>(Whh0, h00, c00,
                                      Wih1, Whh1, bih1, bhh1, h01, c01,
                                      Wih2, Whh2, bih2, bhh2, h02, c02,
                                      Wih3, Whh3, bih3, bhh3, h03, c03,
                                      ws, out);
}